// Round 6
// baseline (284.687 us; speedup 1.0000x reference)
//
#include <hip/hip_runtime.h>
#include <math.h>

// Problem constants
#define BHN    55392           // B*H*N = 8*12*577 tokens; 55392 = 4 * 13848
#define NTOK   577
#define HD     64
#define EPS_F  1e-6f
#define ROWS_PER_BLOCK 4
#define NBLOCKS (BHN / ROWS_PER_BLOCK)   // 13848, exact
#define VEC_PER_BLOCK 577                // 4 rows * 577 elems / 4 per float4

typedef float v4f __attribute__((ext_vector_type(4)));   // nontemporal-friendly

// ---------------------------------------------------------------------------
// Fully fused kernel. One 256-thread block = 4 consecutive token-rows.
//
// Phase 1 (MLP): wave w (lanes 0..63) computes token (4*blk + w)'s coef:
//   lane t: h_t = dot(q_row, W1[:,t])  -- q_row is wave-uniform -> s_loads,
//   W1 column access is coalesced (lane t reads W1[k*64+t]).
//   gelu (A&S erf, branchless), partial s = g*W2 row, 64-lane butterfly
//   reduce, lane 0 does the 2x2-covariance tail -> coef in LDS.
// Phase 2 (mask): all 256 threads stream the block's 577 float4 segment
//   (4*577 floats, 16B-aligned because 4*577*4 B per block). Row-local
//   select (3 compares, no /577), coefs in registers, nontemporal u/out.
//
// Math identities carried from earlier rounds:
//   rowmax(kernel)==1 structurally (j=0 col has w=0; w<=0 since PD), so
//   probs = clip(exp(w), eps, 1-eps); and
//   sigmoid((logits+noise)/0.1) = 1/(1 + r^10), r = (1-p)(1-u)/(p u),
//   r^10 via squaring; r^10 -> inf gives 0, -> 0 gives 1 (correct limits).
// ---------------------------------------------------------------------------
__global__ __launch_bounds__(256) void fused_mask_kernel(
    const float*  __restrict__ q,  const float* __restrict__ W1,
    const float*  __restrict__ b1, const float* __restrict__ W2,
    const float*  __restrict__ b2, const v4f* __restrict__ u4,
    v4f* __restrict__ out4)
{
    __shared__ float4 coef_s[ROWS_PER_BLOCK];

    const int tid  = threadIdx.x;
    const int lane = tid & 63;
    const int wv   = tid >> 6;                       // 0..3: token slot
    const int tok  = blockIdx.x * ROWS_PER_BLOCK + wv;

    // ---------------- Phase 1: per-wave MLP ----------------
    {
        const float* qrow = q + (size_t)tok * HD;    // wave-uniform base
        float h = 0.0f;
        #pragma unroll 8
        for (int k = 0; k < HD; ++k)                 // qrow[k] uniform -> s_load
            h = fmaf(qrow[k], W1[k * HD + lane], h); // coalesced W1 column read

        float x = h + b1[lane];
        // gelu, erf via A&S 7.1.26 (|err|<=1.5e-7), branchless
        float z  = x * 0.70710678118654752f;
        float az = fabsf(z);
        float kk = __builtin_amdgcn_rcpf(fmaf(0.3275911f, az, 1.0f));
        float poly = kk * (0.254829592f + kk * (-0.284496736f +
                     kk * (1.421413741f + kk * (-1.453152027f +
                     kk * 1.061405429f))));
        float om   = poly * __expf(-z * z);          // 1 - erf(|z|)
        float erfz = copysignf(1.0f - om, z);
        float g = 0.5f * x * (1.0f + erfz);

        float s0 = g * W2[lane * 3 + 0];
        float s1 = g * W2[lane * 3 + 1];
        float s2 = g * W2[lane * 3 + 2];

        // 64-lane butterfly reduce
        #pragma unroll
        for (int off = 1; off < 64; off <<= 1) {
            s0 += __shfl_xor(s0, off);
            s1 += __shfl_xor(s1, off);
            s2 += __shfl_xor(s2, off);
        }

        if (lane == 0) {
            s0 += b2[0]; s1 += b2[1]; s2 += b2[2];
            float sx = fmaxf(s0, 0.0f) + 1.0f;
            float sy = fmaxf(s1, 0.0f) + 1.0f;
            float ex = __expf(2.0f * s2);            // tanh via exp
            float rho = 0.99f * ((ex - 1.0f) * __builtin_amdgcn_rcpf(ex + 1.0f));
            float sxx = sx * sx, syy = sy * sy;
            float sxy = rho * sx * sy;
            float det = sxx * syy - sxy * sxy;       // >= 0.0199
            float inv_det = 1.0f / det;

            float a = -0.5f * syy * inv_det;
            float b =  sxy * inv_det;
            float c = -0.5f * sxx * inv_det;

            int i = tok % NTOK;
            float pack;
            if (i == 0) { a = 0.0f; b = 0.0f; c = 0.0f; pack = 0.0f; }
            else {
                int ip = i - 1;
                int ri = ip / 24;
                int ci = ip - ri * 24;
                pack = (float)(ri * 32 + ci);
            }
            coef_s[wv] = make_float4(a, b, c, pack);
        }
    }
    __syncthreads();

    // hold all 4 row-coefs in registers; select per element via cndmask
    const float4 c0 = coef_s[0];
    const float4 c1 = coef_s[1];
    const float4 c2 = coef_s[2];
    const float4 c3 = coef_s[3];

    // ---------------- Phase 2: mask for the 4-row segment ----------------
    const size_t base = (size_t)blockIdx.x * VEC_PER_BLOCK;

    #pragma unroll 1
    for (int it = tid; it < VEC_PER_BLOCK; it += 256) {
        v4f uu = __builtin_nontemporal_load(&u4[base + it]);
        float um[4] = {uu.x, uu.y, uu.z, uu.w};
        float res[4];

        int e0 = it * 4;                             // 0..2304 within segment
        #pragma unroll
        for (int m = 0; m < 4; ++m) {
            int e = e0 + m;
            // row-local select: [0,577) [577,1154) [1154,1731) [1731,2308)
            int rl = (e >= 1731) ? 3 : ((e >= 1154) ? 2 : ((e >= 577) ? 1 : 0));
            int j  = e - rl * 577;
            float4 cf = (rl == 0) ? c0 : ((rl == 1) ? c1 : ((rl == 2) ? c2 : c3));
            int rc = (int)cf.w;

            float dx = 0.0f, dy = 0.0f;
            if (j > 0) {
                unsigned jj = (unsigned)(j - 1);
                unsigned rj = jj / 24u;              // magic-div
                unsigned cj = jj - rj * 24u;
                dx = (float)((rc >> 5) - (int)rj);
                dy = (float)((rc & 31) - (int)cj);
            }

            // w = a*dx^2 + b*dx*dy + c*dy^2  (<= 0)
            float w = fmaf(fmaf(cf.x, dx, cf.y * dy), dx, cf.z * (dy * dy));

            float p = __expf(w);
            p = fminf(fmaxf(p, EPS_F), 1.0f - EPS_F);

            float uk  = um[m];
            float num = p * uk;                      // >= 1e-12
            float den = (1.0f - p) * (1.0f - uk);
            float r   = den * __builtin_amdgcn_rcpf(num);

            float r2  = r * r;
            float r4  = r2 * r2;
            float r5  = r4 * r;
            float r10 = r5 * r5;                     // inf/0 limits correct

            res[m] = __builtin_amdgcn_rcpf(1.0f + r10);
        }

        v4f o = {res[0], res[1], res[2], res[3]};
        __builtin_nontemporal_store(o, &out4[base + it]);
    }
}

// ---------------------------------------------------------------------------
extern "C" void kernel_launch(void* const* d_in, const int* in_sizes, int n_in,
                              void* d_out, int out_size, void* d_ws, size_t ws_size,
                              hipStream_t stream) {
    const float* q  = (const float*)d_in[0];
    const float* W1 = (const float*)d_in[1];
    const float* b1 = (const float*)d_in[2];
    const float* W2 = (const float*)d_in[3];
    const float* b2 = (const float*)d_in[4];
    const float* u  = (const float*)d_in[5];
    // d_in[6] = dists: recomputed on the fly, not loaded. d_ws unused.

    fused_mask_kernel<<<NBLOCKS, 256, 0, stream>>>(
        q, W1, b1, W2, b2, (const v4f*)u, (v4f*)d_out);
}